// Round 12
// baseline (308.513 us; speedup 1.0000x reference)
//
#include <hip/hip_runtime.h>
#include <hip/hip_bf16.h>

#define B_  32
#define N_  577
#define D_  768
#define H_  12
#define HD_ 64
#define M_  (B_ * N_)        // 18464 rows
#define NW_ (3 * D_)         // 2304 fused output cols (q|k|v)
#define VN_ 640              // padded V row stride
#define BPAD_ 640            // bias: padded rows AND cols (pad cols = -1e30)
#define SCALE_ 0.18033688f   // 0.125 * log2(e)  (pre-applied to Q)

typedef __bf16 bf16_t;
typedef __bf16 bf16x8 __attribute__((ext_vector_type(8)));
typedef __bf16 bf16x4 __attribute__((ext_vector_type(4)));
typedef float  f32x4  __attribute__((ext_vector_type(4)));

static __device__ __forceinline__ bf16x8 ldg8(const bf16_t* p) {
    return *reinterpret_cast<const bf16x8*>(p);
}

#define GLOAD_LDS16(g, l)                                                     \
    __builtin_amdgcn_global_load_lds(                                         \
        (const __attribute__((address_space(1))) void*)(g),                   \
        (__attribute__((address_space(3))) void*)(l), 16, 0, 0)

// ---------------------------------------------------------------- fp32->bf16
__global__ void cvt_f32_bf16(const float* __restrict__ src,
                             bf16_t* __restrict__ dst, int n4) {
    int i = blockIdx.x * blockDim.x + threadIdx.x;
    if (i < n4) {
        float4 f = reinterpret_cast<const float4*>(src)[i];
        bf16x4 o;
        o.x = (bf16_t)f.x; o.y = (bf16_t)f.y; o.z = (bf16_t)f.z; o.w = (bf16_t)f.w;
        *reinterpret_cast<bf16x4*>(dst + (size_t)i * 4) = o;
    }
}

__global__ void cvt3_f32_bf16(const float* __restrict__ s0,
                              const float* __restrict__ s1,
                              const float* __restrict__ s2,
                              bf16_t* __restrict__ dst, int n4) {
    int i = blockIdx.x * blockDim.x + threadIdx.x;
    if (i < n4) {
        const float* src = blockIdx.y == 0 ? s0 : (blockIdx.y == 1 ? s1 : s2);
        float4 f = reinterpret_cast<const float4*>(src)[i];
        bf16x4 o;
        o.x = (bf16_t)f.x; o.y = (bf16_t)f.y; o.z = (bf16_t)f.z; o.w = (bf16_t)f.w;
        *reinterpret_cast<bf16x4*>(dst + (size_t)blockIdx.y * n4 * 4 + (size_t)i * 4) = o;
    }
}

// ---------------------------------------------------------------- bias build
__global__ void build_bias_t(const float* __restrict__ table,
                             const int* __restrict__ idx,
                             float* __restrict__ biasT) {
    int col = blockIdx.x;   // 0..639
    int h   = blockIdx.y;
    float* dst = biasT + ((size_t)h * BPAD_ + col) * BPAD_;
    if (col < N_) {
        for (int row = threadIdx.x; row < BPAD_; row += blockDim.x) {
            int rr = row < N_ ? row : (N_ - 1);
            int id = idx[rr * N_ + col];
            dst[row] = table[id * H_ + h] * 1.44269504f;
        }
    } else {
        for (int row = threadIdx.x; row < BPAD_; row += blockDim.x)
            dst[row] = -1e30f;
    }
}

// ---------------------------------------------------------------- QKV GEMM
// (round-9 version: 128x128 tile, BK=64, dbuf + counted vmcnt(8))
__global__ __launch_bounds__(256) void qkv_gemm(
    const bf16_t* __restrict__ hb, const bf16_t* __restrict__ W,
    const float* __restrict__ qb, const float* __restrict__ vb,
    bf16_t* __restrict__ Q, bf16_t* __restrict__ K, bf16_t* __restrict__ VT)
{
    __shared__ __align__(16) char lds[65536];  // A:[2][16K] @0, B:[2][16K] @32K

    int tid = threadIdx.x;
    int w  = tid >> 6, l = tid & 63;
    int lr = l & 15, lg = l >> 4;
    int wm = w & 1,  wn = w >> 1;

    int wg = blockIdx.x;
    int xcd = wg & 7, pos = wg >> 3;
    const int Q8 = 2610 / 8, R8 = 2610 % 8;   // 326, 2
    int base = xcd < R8 ? xcd * (Q8 + 1) : R8 * (Q8 + 1) + (xcd - R8) * Q8;
    int wgid = base + pos;
    int bx = wgid / 18, y = wgid - bx * 18;
    int brow = bx * 128;
    int mat = y / 6, ysub = y - mat * 6;
    int cbase = ysub * 128;

    int srow = tid >> 3;
    int sslot = (tid & 7) ^ (srow & 7);
    const bf16_t* pa[4];
    const bf16_t* pb[4];
#pragma unroll
    for (int r = 0; r < 4; ++r) {
        int ra = brow + r * 32 + srow; ra = ra < M_ ? ra : (M_ - 1);
        pa[r] = hb + (size_t)ra * D_ + sslot * 8;
        pb[r] = W + (size_t)(y * 128 + r * 32 + srow) * D_ + sslot * 8;
    }

    auto stage = [&](int buf, int k) {
#pragma unroll
        for (int r = 0; r < 4; ++r) {
            GLOAD_LDS16(pa[r] + k, lds + buf * 16384 + r * 4096 + tid * 16);
            GLOAD_LDS16(pb[r] + k, lds + 32768 + buf * 16384 + r * 4096 + tid * 16);
        }
    };

    f32x4 acc[4][4] = {};
    stage(0, 0);
    int cur = 0;
    for (int t = 0; t < 12; ++t) {
        if (t < 11) {
            stage(cur ^ 1, (t + 1) * 64);
            asm volatile("s_waitcnt vmcnt(8)" ::: "memory");
        } else {
            asm volatile("s_waitcnt vmcnt(0)" ::: "memory");
        }
        __builtin_amdgcn_s_barrier();
        __builtin_amdgcn_sched_barrier(0);

        const char* pA = lds + cur * 16384;
        const char* pB = lds + 32768 + cur * 16384;
#pragma unroll
        for (int kk = 0; kk < 2; ++kk) {
            bf16x8 af[4];
#pragma unroll
            for (int m = 0; m < 4; ++m) {
                int row = wm * 64 + m * 16 + lr;
                af[m] = *reinterpret_cast<const bf16x8*>(
                    pA + row * 128 + (((kk * 4 + lg) ^ (lr & 7)) << 4));
            }
#pragma unroll
            for (int n = 0; n < 4; ++n) {
                int row = wn * 64 + n * 16 + lr;
                bf16x8 bfr = *reinterpret_cast<const bf16x8*>(
                    pB + row * 128 + (((kk * 4 + lg) ^ (lr & 7)) << 4));
#pragma unroll
                for (int m = 0; m < 4; ++m)
                    acc[m][n] = __builtin_amdgcn_mfma_f32_16x16x32_bf16(
                        af[m], bfr, acc[m][n], 0, 0, 0);
            }
        }
        __builtin_amdgcn_sched_barrier(0);
        __builtin_amdgcn_s_barrier();
        cur ^= 1;
    }

    bf16_t* ep = (bf16_t*)lds;
    if (mat < 2) {
#pragma unroll
        for (int m = 0; m < 4; ++m)
#pragma unroll
            for (int n = 0; n < 4; ++n) {
                int col = wn * 64 + n * 16 + lr;
#pragma unroll
                for (int j = 0; j < 4; ++j) {
                    int row = wm * 64 + m * 16 + lg * 4 + j;
                    float v = acc[m][n][j];
                    v = (mat == 0) ? (v + qb[cbase + col]) * SCALE_ : v;
                    ep[row * 132 + col] = (bf16_t)v;
                }
            }
        __syncthreads();
        bf16_t* dst0 = (mat == 0) ? Q : K;
#pragma unroll
        for (int k = 0; k < 8; ++k) {
            int c = k * 256 + tid;
            int row = c >> 4, cc = c & 15;
            int grow = brow + row;
            if (grow < M_) {
                int bb = grow / N_, nn = grow - bb * N_;
                int col0 = cc * 8;
                int hh = ysub * 2 + (col0 >> 6);
                int hd0 = col0 & 63;
                bf16x8 vc = *reinterpret_cast<const bf16x8*>(ep + row * 132 + col0);
                *reinterpret_cast<bf16x8*>(
                    dst0 + ((size_t)(bb * H_ + hh) * N_ + nn) * HD_ + hd0) = vc;
            }
        }
    } else {
#pragma unroll
        for (int m = 0; m < 4; ++m)
#pragma unroll
            for (int n = 0; n < 4; ++n) {
                int col = wn * 64 + n * 16 + lr;
                float badd = vb[cbase + col];
#pragma unroll
                for (int j = 0; j < 4; ++j) {
                    int row = wm * 64 + m * 16 + lg * 4 + j;
                    ep[col * 132 + row] = (bf16_t)(acc[m][n][j] + badd);
                }
            }
        __syncthreads();
#pragma unroll
        for (int k = 0; k < 8; ++k) {
            int c = k * 256 + tid;
            int col = c >> 4, rc = c & 15;
            int grow0 = brow + rc * 8;
            int hh = ysub * 2 + (col >> 6), hd = col & 63;
            int bb = grow0 / N_, nn0 = grow0 - bb * N_;
            if (nn0 + 8 <= N_ && grow0 + 8 <= M_) {
                *reinterpret_cast<bf16x8*>(
                    VT + ((size_t)(bb * H_ + hh) * HD_ + hd) * VN_ + nn0) =
                    *reinterpret_cast<const bf16x8*>(ep + col * 132 + rc * 8);
            } else {
                for (int jj = 0; jj < 8; ++jj) {
                    int grow = grow0 + jj;
                    if (grow >= M_) break;
                    int b2 = grow / N_, n2 = grow - b2 * N_;
                    VT[((size_t)(b2 * H_ + hh) * HD_ + hd) * VN_ + n2] =
                        ep[col * 132 + rc * 8 + jj];
                }
            }
        }
    }
}

// ---------------------------------------------------------------- attention
// 2 q-frags per wave (32 q-rows/wave, 128/block): K/V LDS fragment reads are
// shared across the two frags -> LDS-pipe cycles per MFMA drop ~40% (the
// measured bottleneck). One-barrier pipeline: K,V dbuf; bias reg-dbuf for
// both frags; nothing issued in tile t is consumed in tile t.
__global__ __launch_bounds__(256) void attn(
    const bf16_t* __restrict__ Q, const bf16_t* __restrict__ K,
    const bf16_t* __restrict__ VT, const float* __restrict__ biasT,
    float* __restrict__ out)
{
    __shared__ __align__(16) char Kl[2][8192];      // [64 key][64 hd] swz
    __shared__ __align__(16) char Vl[2][8192];      // [64 d][64 key] swz
    __shared__ __align__(16) char Pl[4][2][2048];   // per-wave, per-frag P
    // 49152 B -> 3 blocks/CU

    int tid = threadIdx.x;
    int w = tid >> 6, l = tid & 63, lr = l & 15, lg = l >> 4;

    // 1920 blocks = 240/XCD; h slowest within chunk
    int wg = blockIdx.x;
    int wgid = (wg & 7) * 240 + (wg >> 3);
    int h = wgid / 160;
    int rem = wgid - h * 160;
    int b = rem / 5;
    int qt = rem - b * 5;

    const bf16_t* Qp = Q  + (size_t)(b * H_ + h) * N_ * HD_;
    const bf16_t* Kp = K  + (size_t)(b * H_ + h) * N_ * HD_;
    const bf16_t* Vp = VT + (size_t)(b * H_ + h) * HD_ * VN_;
    const float*  bp = biasT + (size_t)h * BPAD_ * BPAD_;   // [col][row]

    int q0A = qt * 128 + w * 16;
    int q0B = q0A + 64;
    bf16x8 aQ0A, aQ1A, aQ0B, aQ1B;
    {
        int qa = q0A + lr; qa = qa < N_ ? qa : (N_ - 1);
        int qb2 = q0B + lr; qb2 = qb2 < N_ ? qb2 : (N_ - 1);
        aQ0A = ldg8(Qp + (size_t)qa * HD_ + lg * 8);
        aQ1A = ldg8(Qp + (size_t)qa * HD_ + 32 + lg * 8);
        aQ0B = ldg8(Qp + (size_t)qb2 * HD_ + lg * 8);
        aQ1B = ldg8(Qp + (size_t)qb2 * HD_ + 32 + lg * 8);
    }

    bf16x8 vone;
#pragma unroll
    for (int i = 0; i < 8; ++i) vone[i] = (bf16_t)1.0f;

    int rloc = l >> 3;
    int cswz = (l & 7) ^ rloc;
    const bf16_t* Kst[2];
    const bf16_t* Vst[2];
#pragma unroll
    for (int rnd = 0; rnd < 2; ++rnd) {
        int r = rnd * 32 + w * 8 + rloc;
        Kst[rnd] = Kp + (size_t)r * HD_ + cswz * 8;   // unclamped (padded buf)
        Vst[rnd] = Vp + (size_t)r * VN_ + cswz * 8;
    }

    f32x4 oA[4] = {}, oB[4] = {};
    f32x4 osumA = {}, osumB = {};
    char* PwA = Pl[w][0];
    char* PwB = Pl[w][1];
    const int NT = 10;

    auto stageKV = [&](int buf, int k0) {
#pragma unroll
        for (int rnd = 0; rnd < 2; ++rnd)
            GLOAD_LDS16(Kst[rnd] + (size_t)k0 * HD_,
                        Kl[buf] + rnd * 4096 + w * 1024);
#pragma unroll
        for (int rnd = 0; rnd < 2; ++rnd)
            GLOAD_LDS16(Vst[rnd] + k0, Vl[buf] + rnd * 4096 + w * 1024);
    };
    auto loadBias = [&](int k0, f32x4* bA, f32x4* bB) {
#pragma unroll
        for (int kt = 0; kt < 4; ++kt) {
            const float* bcol = bp + (size_t)(k0 + kt * 16 + lr) * BPAD_;
            bA[kt] = *reinterpret_cast<const f32x4*>(bcol + q0A + lg * 4);
            bB[kt] = *reinterpret_cast<const f32x4*>(bcol + q0B + lg * 4);
        }
    };

    // one tile: read buf rbuf + bias (bcA,bcB); prefetch into rbuf^1 + (bnA,bnB)
    auto tile = [&](int t, int rbuf, const f32x4* bcA, const f32x4* bcB,
                    f32x4* bnA, f32x4* bnB) {
        int k0 = t * 64;
        if (t + 1 < NT) {
            stageKV(rbuf ^ 1, k0 + 64);           // 4 loads (oldest)
            loadBias(k0 + 64, bnA, bnB);          // 8 loads (youngest)
        }
        __builtin_amdgcn_sched_barrier(0);

        // S = Q K^T + bias (C-init; Q pre-scaled); K frags shared across frags
        f32x4 sA[4], sB[4];
        __builtin_amdgcn_s_setprio(1);
#pragma unroll
        for (int kt = 0; kt < 4; ++kt) {
            int r = kt * 16 + lr;
            bf16x8 kf0 = *reinterpret_cast<const bf16x8*>(
                Kl[rbuf] + r * 128 + ((lg ^ (r & 7)) << 4));
            bf16x8 kf1 = *reinterpret_cast<const bf16x8*>(
                Kl[rbuf] + r * 128 + (((4 + lg) ^ (r & 7)) << 4));
            f32x4 a0 = __builtin_amdgcn_mfma_f32_16x16x32_bf16(
                aQ0A, kf0, bcA[kt], 0, 0, 0);
            sA[kt] = __builtin_amdgcn_mfma_f32_16x16x32_bf16(aQ1A, kf1, a0, 0, 0, 0);
            f32x4 a1 = __builtin_amdgcn_mfma_f32_16x16x32_bf16(
                aQ0B, kf0, bcB[kt], 0, 0, 0);
            sB[kt] = __builtin_amdgcn_mfma_f32_16x16x32_bf16(aQ1B, kf1, a1, 0, 0, 0);
        }
        __builtin_amdgcn_s_setprio(0);

        // P = exp2(s) -> per-wave per-frag LDS (wave-local, no block barrier)
#pragma unroll
        for (int kt = 0; kt < 4; ++kt)
#pragma unroll
            for (int j = 0; j < 4; ++j) {
                int row = lg * 4 + j;
                int byte = (row * 128 + (kt * 16 + lr) * 2) ^ ((row & 7) << 4);
                *reinterpret_cast<bf16_t*>(PwA + byte) =
                    (bf16_t)__builtin_amdgcn_exp2f(sA[kt][j]);
                *reinterpret_cast<bf16_t*>(PwB + byte) =
                    (bf16_t)__builtin_amdgcn_exp2f(sB[kt][j]);
            }

        // O += P V ; row-sum += P * ones; V frags shared across frags
        __builtin_amdgcn_s_setprio(1);
#pragma unroll
        for (int kc = 0; kc < 2; ++kc) {
            int pbyte = (lr * 128 + kc * 64 + lg * 16) ^ ((lr & 7) << 4);
            bf16x8 aPA = *reinterpret_cast<const bf16x8*>(PwA + pbyte);
            bf16x8 aPB = *reinterpret_cast<const bf16x8*>(PwB + pbyte);
            osumA = __builtin_amdgcn_mfma_f32_16x16x32_bf16(aPA, vone, osumA, 0, 0, 0);
            osumB = __builtin_amdgcn_mfma_f32_16x16x32_bf16(aPB, vone, osumB, 0, 0, 0);
#pragma unroll
            for (int ft = 0; ft < 4; ++ft) {
                int d = ft * 16 + lr;
                bf16x8 bV = *reinterpret_cast<const bf16x8*>(
                    Vl[rbuf] + d * 128 + (((kc * 4 + lg) ^ (d & 7)) << 4));
                oA[ft] = __builtin_amdgcn_mfma_f32_16x16x32_bf16(aPA, bV, oA[ft], 0, 0, 0);
                oB[ft] = __builtin_amdgcn_mfma_f32_16x16x32_bf16(aPB, bV, oB[ft], 0, 0, 0);
            }
        }
        __builtin_amdgcn_s_setprio(0);
        __builtin_amdgcn_sched_barrier(0);

        // own stage(t+1) landed (bias(t+1) may stay in flight) -> barrier
        if (t + 1 < NT) asm volatile("s_waitcnt vmcnt(8)" ::: "memory");
        else            asm volatile("s_waitcnt vmcnt(0)" ::: "memory");
        __builtin_amdgcn_s_barrier();
        __builtin_amdgcn_sched_barrier(0);
    };

    // prologue: stage tile 0 + bias 0
    f32x4 bbA0[4], bbB0[4], bbA1[4], bbB1[4];
    stageKV(0, 0);
    loadBias(0, bbA0, bbB0);
    asm volatile("s_waitcnt vmcnt(8)" ::: "memory");   // stages landed
    __builtin_amdgcn_s_barrier();
    __builtin_amdgcn_sched_barrier(0);

    // NT=10: 5 unrolled pairs; even tiles buf0/pair0, odd buf1/pair1
    for (int tp = 0; tp < NT / 2; ++tp) {
        tile(tp * 2,     0, bbA0, bbB0, bbA1, bbB1);
        tile(tp * 2 + 1, 1, bbA1, bbB1, bbA0, bbB0);
    }

#pragma unroll
    for (int j = 0; j < 4; ++j) {
        int rowA = q0A + lg * 4 + j;
        if (rowA < N_) {
            float inv = 1.f / osumA[j];
#pragma unroll
            for (int ft = 0; ft < 4; ++ft)
                out[((size_t)(b * N_ + rowA)) * D_ + h * HD_ + ft * 16 + lr] =
                    oA[ft][j] * inv;
        }
        int rowB = q0B + lg * 4 + j;
        if (rowB < N_) {
            float inv = 1.f / osumB[j];
#pragma unroll
            for (int ft = 0; ft < 4; ++ft)
                out[((size_t)(b * N_ + rowB)) * D_ + h * HD_ + ft * 16 + lr] =
                    oB[ft][j] * inv;
        }
    }
}

// ---------------------------------------------------------------- launch
extern "C" void kernel_launch(void* const* d_in, const int* in_sizes, int n_in,
                              void* d_out, int out_size, void* d_ws, size_t ws_size,
                              hipStream_t stream)
{
    const float* hs    = (const float*)d_in[0];
    const float* q_w   = (const float*)d_in[1];
    const float* q_b   = (const float*)d_in[2];
    const float* k_w   = (const float*)d_in[3];
    const float* v_w   = (const float*)d_in[4];
    const float* v_b   = (const float*)d_in[5];
    const float* table = (const float*)d_in[6];
    const int*   rpi   = (const int*)d_in[7];
    float* out = (float*)d_out;

    char* ws = (char*)d_ws;
    size_t off = 0;
    auto alloc = [&](size_t bytes) {
        char* p = ws + off;
        off = (off + bytes + 255) & ~(size_t)255;
        return p;
    };
    bf16_t* hb  = (bf16_t*)alloc((size_t)M_ * D_ * 2);
    bf16_t* Wc  = (bf16_t*)alloc((size_t)NW_ * D_ * 2);
    bf16_t* Qb  = (bf16_t*)alloc((size_t)B_ * H_ * N_ * HD_ * 2);
    bf16_t* Kb  = (bf16_t*)alloc((size_t)B_ * H_ * N_ * HD_ * 2 + 16384); // +pad rows
    bf16_t* VTb = (bf16_t*)alloc((size_t)B_ * H_ * HD_ * VN_ * 2);
    float*  bia = (float*)alloc((size_t)H_ * BPAD_ * BPAD_ * 4);

    int n4h = M_ * D_ / 4;
    cvt_f32_bf16<<<(n4h + 255) / 256, 256, 0, stream>>>(hs, hb, n4h);
    int n4w = D_ * D_ / 4;
    cvt3_f32_bf16<<<dim3((n4w + 255) / 256, 3), 256, 0, stream>>>(
        q_w, k_w, v_w, Wc, n4w);
    build_bias_t<<<dim3(BPAD_, H_), 256, 0, stream>>>(table, rpi, bia);

    qkv_gemm<<<2610, 256, 0, stream>>>(hb, Wc, q_b, v_b, Qb, Kb, VTb);

    attn<<<1920, 256, 0, stream>>>(Qb, Kb, VTb, bia, out);
}

// Round 13
// 218.828 us; speedup vs baseline: 1.4098x; 1.4098x over previous
//
#include <hip/hip_runtime.h>
#include <hip/hip_bf16.h>

#define B_  32
#define N_  577
#define D_  768
#define H_  12
#define HD_ 64
#define M_  (B_ * N_)        // 18464 rows
#define NW_ (3 * D_)         // 2304 fused output cols (q|k|v)
#define VN_ 640              // padded V row stride
#define BPAD_ 640            // bias: padded rows AND cols (pad cols = -1e30)
#define SCALE_ 0.18033688f   // 0.125 * log2(e)  (pre-applied to Q)

typedef __bf16 bf16_t;
typedef __bf16 bf16x8 __attribute__((ext_vector_type(8)));
typedef __bf16 bf16x4 __attribute__((ext_vector_type(4)));
typedef float  f32x4  __attribute__((ext_vector_type(4)));

static __device__ __forceinline__ bf16x8 ldg8(const bf16_t* p) {
    return *reinterpret_cast<const bf16x8*>(p);
}

#define GLOAD_LDS16(g, l)                                                     \
    __builtin_amdgcn_global_load_lds(                                         \
        (const __attribute__((address_space(1))) void*)(g),                   \
        (__attribute__((address_space(3))) void*)(l), 16, 0, 0)

// ---------------------------------------------------------------- fp32->bf16
__global__ void cvt_f32_bf16(const float* __restrict__ src,
                             bf16_t* __restrict__ dst, int n4) {
    int i = blockIdx.x * blockDim.x + threadIdx.x;
    if (i < n4) {
        float4 f = reinterpret_cast<const float4*>(src)[i];
        bf16x4 o;
        o.x = (bf16_t)f.x; o.y = (bf16_t)f.y; o.z = (bf16_t)f.z; o.w = (bf16_t)f.w;
        *reinterpret_cast<bf16x4*>(dst + (size_t)i * 4) = o;
    }
}

__global__ void cvt3_f32_bf16(const float* __restrict__ s0,
                              const float* __restrict__ s1,
                              const float* __restrict__ s2,
                              bf16_t* __restrict__ dst, int n4) {
    int i = blockIdx.x * blockDim.x + threadIdx.x;
    if (i < n4) {
        const float* src = blockIdx.y == 0 ? s0 : (blockIdx.y == 1 ? s1 : s2);
        float4 f = reinterpret_cast<const float4*>(src)[i];
        bf16x4 o;
        o.x = (bf16_t)f.x; o.y = (bf16_t)f.y; o.z = (bf16_t)f.z; o.w = (bf16_t)f.w;
        *reinterpret_cast<bf16x4*>(dst + (size_t)blockIdx.y * n4 * 4 + (size_t)i * 4) = o;
    }
}

// ---------------------------------------------------------------- bias build
// One block per key-column; h-loop inside so idx[row][col] is read ONCE
// (was 12x). biasT[h][col][row] = table[idx[row][col]*H + h] * log2(e);
// cols [N_,640) get -1e30 (kills padded keys via the MFMA C-init).
__global__ void build_bias_t(const float* __restrict__ table,
                             const int* __restrict__ idx,
                             float* __restrict__ biasT) {
    int col = blockIdx.x;   // 0..639
    if (col < N_) {
        for (int row = threadIdx.x; row < BPAD_; row += blockDim.x) {
            int rr = row < N_ ? row : (N_ - 1);
            int id = idx[rr * N_ + col];
            const float* trow = table + (size_t)id * H_;
#pragma unroll
            for (int h = 0; h < H_; ++h)
                biasT[((size_t)h * BPAD_ + col) * BPAD_ + row] =
                    trow[h] * 1.44269504f;
        }
    } else {
        for (int row = threadIdx.x; row < BPAD_; row += blockDim.x) {
#pragma unroll
            for (int h = 0; h < H_; ++h)
                biasT[((size_t)h * BPAD_ + col) * BPAD_ + row] = -1e30f;
        }
    }
}

// ---------------------------------------------------------------- QKV GEMM
// (round-9/11 version: 128x128 tile, BK=64, dbuf + counted vmcnt(8))
__global__ __launch_bounds__(256) void qkv_gemm(
    const bf16_t* __restrict__ hb, const bf16_t* __restrict__ W,
    const float* __restrict__ qb, const float* __restrict__ vb,
    bf16_t* __restrict__ Q, bf16_t* __restrict__ K, bf16_t* __restrict__ VT)
{
    __shared__ __align__(16) char lds[65536];  // A:[2][16K] @0, B:[2][16K] @32K

    int tid = threadIdx.x;
    int w  = tid >> 6, l = tid & 63;
    int lr = l & 15, lg = l >> 4;
    int wm = w & 1,  wn = w >> 1;

    int wg = blockIdx.x;
    int xcd = wg & 7, pos = wg >> 3;
    const int Q8 = 2610 / 8, R8 = 2610 % 8;   // 326, 2
    int base = xcd < R8 ? xcd * (Q8 + 1) : R8 * (Q8 + 1) + (xcd - R8) * Q8;
    int wgid = base + pos;
    int bx = wgid / 18, y = wgid - bx * 18;
    int brow = bx * 128;
    int mat = y / 6, ysub = y - mat * 6;
    int cbase = ysub * 128;

    int srow = tid >> 3;
    int sslot = (tid & 7) ^ (srow & 7);
    const bf16_t* pa[4];
    const bf16_t* pb[4];
#pragma unroll
    for (int r = 0; r < 4; ++r) {
        int ra = brow + r * 32 + srow; ra = ra < M_ ? ra : (M_ - 1);
        pa[r] = hb + (size_t)ra * D_ + sslot * 8;
        pb[r] = W + (size_t)(y * 128 + r * 32 + srow) * D_ + sslot * 8;
    }

    auto stage = [&](int buf, int k) {
#pragma unroll
        for (int r = 0; r < 4; ++r) {
            GLOAD_LDS16(pa[r] + k, lds + buf * 16384 + r * 4096 + tid * 16);
            GLOAD_LDS16(pb[r] + k, lds + 32768 + buf * 16384 + r * 4096 + tid * 16);
        }
    };

    f32x4 acc[4][4] = {};
    stage(0, 0);
    int cur = 0;
    for (int t = 0; t < 12; ++t) {
        if (t < 11) {
            stage(cur ^ 1, (t + 1) * 64);
            asm volatile("s_waitcnt vmcnt(8)" ::: "memory");
        } else {
            asm volatile("s_waitcnt vmcnt(0)" ::: "memory");
        }
        __builtin_amdgcn_s_barrier();
        __builtin_amdgcn_sched_barrier(0);

        const char* pA = lds + cur * 16384;
        const char* pB = lds + 32768 + cur * 16384;
#pragma unroll
        for (int kk = 0; kk < 2; ++kk) {
            bf16x8 af[4];
#pragma unroll
            for (int m = 0; m < 4; ++m) {
                int row = wm * 64 + m * 16 + lr;
                af[m] = *reinterpret_cast<const bf16x8*>(
                    pA + row * 128 + (((kk * 4 + lg) ^ (lr & 7)) << 4));
            }
#pragma unroll
            for (int n = 0; n < 4; ++n) {
                int row = wn * 64 + n * 16 + lr;
                bf16x8 bfr = *reinterpret_cast<const bf16x8*>(
                    pB + row * 128 + (((kk * 4 + lg) ^ (lr & 7)) << 4));
#pragma unroll
                for (int m = 0; m < 4; ++m)
                    acc[m][n] = __builtin_amdgcn_mfma_f32_16x16x32_bf16(
                        af[m], bfr, acc[m][n], 0, 0, 0);
            }
        }
        __builtin_amdgcn_sched_barrier(0);
        __builtin_amdgcn_s_barrier();
        cur ^= 1;
    }

    bf16_t* ep = (bf16_t*)lds;
    if (mat < 2) {
#pragma unroll
        for (int m = 0; m < 4; ++m)
#pragma unroll
            for (int n = 0; n < 4; ++n) {
                int col = wn * 64 + n * 16 + lr;
#pragma unroll
                for (int j = 0; j < 4; ++j) {
                    int row = wm * 64 + m * 16 + lg * 4 + j;
                    float v = acc[m][n][j];
                    v = (mat == 0) ? (v + qb[cbase + col]) * SCALE_ : v;
                    ep[row * 132 + col] = (bf16_t)v;
                }
            }
        __syncthreads();
        bf16_t* dst0 = (mat == 0) ? Q : K;
#pragma unroll
        for (int k = 0; k < 8; ++k) {
            int c = k * 256 + tid;
            int row = c >> 4, cc = c & 15;
            int grow = brow + row;
            if (grow < M_) {
                int bb = grow / N_, nn = grow - bb * N_;
                int col0 = cc * 8;
                int hh = ysub * 2 + (col0 >> 6);
                int hd0 = col0 & 63;
                bf16x8 vc = *reinterpret_cast<const bf16x8*>(ep + row * 132 + col0);
                *reinterpret_cast<bf16x8*>(
                    dst0 + ((size_t)(bb * H_ + hh) * N_ + nn) * HD_ + hd0) = vc;
            }
        }
    } else {
#pragma unroll
        for (int m = 0; m < 4; ++m)
#pragma unroll
            for (int n = 0; n < 4; ++n) {
                int col = wn * 64 + n * 16 + lr;
                float badd = vb[cbase + col];
#pragma unroll
                for (int j = 0; j < 4; ++j) {
                    int row = wm * 64 + m * 16 + lg * 4 + j;
                    ep[col * 132 + row] = (bf16_t)(acc[m][n][j] + badd);
                }
            }
        __syncthreads();
#pragma unroll
        for (int k = 0; k < 8; ++k) {
            int c = k * 256 + tid;
            int col = c >> 4, rc = c & 15;
            int grow0 = brow + rc * 8;
            int hh = ysub * 2 + (col >> 6), hd = col & 63;
            int bb = grow0 / N_, nn0 = grow0 - bb * N_;
            if (nn0 + 8 <= N_ && grow0 + 8 <= M_) {
                *reinterpret_cast<bf16x8*>(
                    VT + ((size_t)(bb * H_ + hh) * HD_ + hd) * VN_ + nn0) =
                    *reinterpret_cast<const bf16x8*>(ep + col * 132 + rc * 8);
            } else {
                for (int jj = 0; jj < 8; ++jj) {
                    int grow = grow0 + jj;
                    if (grow >= M_) break;
                    int b2 = grow / N_, n2 = grow - b2 * N_;
                    VT[((size_t)(b2 * H_ + hh) * HD_ + hd) * VN_ + n2] =
                        ep[col * 132 + rc * 8 + jj];
                }
            }
        }
    }
}

// ---------------------------------------------------------------- attention
// (round-11 version — best measured: 120 us. One-barrier pipeline: K,V dbuf,
// bias reg-dbuf; nothing issued in tile t is consumed in tile t; per tile one
// counted vmcnt + one s_barrier. P per-wave LDS, no block barrier for PV.)
__global__ __launch_bounds__(256) void attn(
    const bf16_t* __restrict__ Q, const bf16_t* __restrict__ K,
    const bf16_t* __restrict__ VT, const float* __restrict__ biasT,
    float* __restrict__ out)
{
    __shared__ __align__(16) char Kl[2][8192];   // [64 key][64 hd] swz
    __shared__ __align__(16) char Vl[2][8192];   // [64 d][64 key] swz
    __shared__ __align__(16) char Pl[4][2048];   // per-wave P, swz
    // 40960 B -> 4 blocks/CU

    int tid = threadIdx.x;
    int w = tid >> 6, l = tid & 63, lr = l & 15, lg = l >> 4;

    int wg = blockIdx.x;
    int wgid = (wg & 7) * 480 + (wg >> 3);
    int h = wgid / 320;
    int rem = wgid - h * 320;
    int b = rem / 10;
    int qt = rem - b * 10;

    const bf16_t* Qp = Q  + (size_t)(b * H_ + h) * N_ * HD_;
    const bf16_t* Kp = K  + (size_t)(b * H_ + h) * N_ * HD_;
    const bf16_t* Vp = VT + (size_t)(b * H_ + h) * HD_ * VN_;
    const float*  bp = biasT + (size_t)h * BPAD_ * BPAD_;   // [col][row]

    int q0 = qt * 64 + w * 16;
    int qrow = q0 + lr;
    int qrow_c = qrow < N_ ? qrow : (N_ - 1);
    bf16x8 aQ0 = ldg8(Qp + (size_t)qrow_c * HD_ + lg * 8);
    bf16x8 aQ1 = ldg8(Qp + (size_t)qrow_c * HD_ + 32 + lg * 8);

    bf16x8 vone;
#pragma unroll
    for (int i = 0; i < 8; ++i) vone[i] = (bf16_t)1.0f;

    int rloc = l >> 3;
    int cswz = (l & 7) ^ rloc;
    const bf16_t* Kst[2];
    const bf16_t* Vst[2];
#pragma unroll
    for (int rnd = 0; rnd < 2; ++rnd) {
        int r = rnd * 32 + w * 8 + rloc;
        Kst[rnd] = Kp + (size_t)r * HD_ + cswz * 8;   // unclamped (padded buf)
        Vst[rnd] = Vp + (size_t)r * VN_ + cswz * 8;
    }

    f32x4 o[4] = {};
    f32x4 osum = {};
    char* Pw = Pl[w];
    const int NT = 10;

    auto stageKV = [&](int buf, int k0) {
#pragma unroll
        for (int rnd = 0; rnd < 2; ++rnd)
            GLOAD_LDS16(Kst[rnd] + (size_t)k0 * HD_,
                        Kl[buf] + rnd * 4096 + w * 1024);
#pragma unroll
        for (int rnd = 0; rnd < 2; ++rnd)
            GLOAD_LDS16(Vst[rnd] + k0, Vl[buf] + rnd * 4096 + w * 1024);
    };
    auto loadBias = [&](int k0, f32x4* bbv) {
#pragma unroll
        for (int kt = 0; kt < 4; ++kt)
            bbv[kt] = *reinterpret_cast<const f32x4*>(
                bp + (size_t)(k0 + kt * 16 + lr) * BPAD_ + q0 + lg * 4);
    };

    auto tile = [&](int t, int rbuf, const f32x4* bbcur, f32x4* bbnxt) {
        int k0 = t * 64;
        if (t + 1 < NT) {
            stageKV(rbuf ^ 1, k0 + 64);
            loadBias(k0 + 64, bbnxt);
        }
        __builtin_amdgcn_sched_barrier(0);

        // S = Q K^T + bias (C-init; Q pre-scaled)
        f32x4 s[4];
        __builtin_amdgcn_s_setprio(1);
#pragma unroll
        for (int kt = 0; kt < 4; ++kt) {
            int r = kt * 16 + lr;
            bf16x8 kf0 = *reinterpret_cast<const bf16x8*>(
                Kl[rbuf] + r * 128 + ((lg ^ (r & 7)) << 4));
            bf16x8 kf1 = *reinterpret_cast<const bf16x8*>(
                Kl[rbuf] + r * 128 + (((4 + lg) ^ (r & 7)) << 4));
            f32x4 a = __builtin_amdgcn_mfma_f32_16x16x32_bf16(
                aQ0, kf0, bbcur[kt], 0, 0, 0);
            s[kt] = __builtin_amdgcn_mfma_f32_16x16x32_bf16(aQ1, kf1, a, 0, 0, 0);
        }
        __builtin_amdgcn_s_setprio(0);

        // P = exp2(s) -> per-wave LDS
#pragma unroll
        for (int kt = 0; kt < 4; ++kt)
#pragma unroll
            for (int j = 0; j < 4; ++j) {
                float p = __builtin_amdgcn_exp2f(s[kt][j]);
                int row = lg * 4 + j;
                int byte = (row * 128 + (kt * 16 + lr) * 2) ^ ((row & 7) << 4);
                *reinterpret_cast<bf16_t*>(Pw + byte) = (bf16_t)p;
            }

        // O += P V ; row-sum += P * ones
        __builtin_amdgcn_s_setprio(1);
#pragma unroll
        for (int kc = 0; kc < 2; ++kc) {
            int pbyte = (lr * 128 + kc * 64 + lg * 16) ^ ((lr & 7) << 4);
            bf16x8 aP = *reinterpret_cast<const bf16x8*>(Pw + pbyte);
            osum = __builtin_amdgcn_mfma_f32_16x16x32_bf16(aP, vone, osum, 0, 0, 0);
#pragma unroll
            for (int ft = 0; ft < 4; ++ft) {
                int d = ft * 16 + lr;
                bf16x8 bV = *reinterpret_cast<const bf16x8*>(
                    Vl[rbuf] + d * 128 + (((kc * 4 + lg) ^ (d & 7)) << 4));
                o[ft] = __builtin_amdgcn_mfma_f32_16x16x32_bf16(aP, bV, o[ft], 0, 0, 0);
            }
        }
        __builtin_amdgcn_s_setprio(0);
        __builtin_amdgcn_sched_barrier(0);

        if (t + 1 < NT) asm volatile("s_waitcnt vmcnt(4)" ::: "memory");
        else            asm volatile("s_waitcnt vmcnt(0)" ::: "memory");
        __builtin_amdgcn_s_barrier();
        __builtin_amdgcn_sched_barrier(0);
    };

    f32x4 bbA[4], bbB[4];
    stageKV(0, 0);
    loadBias(0, bbA);
    asm volatile("s_waitcnt vmcnt(4)" ::: "memory");
    __builtin_amdgcn_s_barrier();
    __builtin_amdgcn_sched_barrier(0);

    for (int tp = 0; tp < NT / 2; ++tp) {
        tile(tp * 2,     0, bbA, bbB);
        tile(tp * 2 + 1, 1, bbB, bbA);
    }

#pragma unroll
    for (int j = 0; j < 4; ++j) {
        int row = q0 + lg * 4 + j;
        if (row < N_) {
            float inv = 1.f / osum[j];
#pragma unroll
            for (int ft = 0; ft < 4; ++ft)
                out[((size_t)(b * N_ + row)) * D_ + h * HD_ + ft * 16 + lr] =
                    o[ft][j] * inv;
        }
    }
}

// ---------------------------------------------------------------- launch
extern "C" void kernel_launch(void* const* d_in, const int* in_sizes, int n_in,
                              void* d_out, int out_size, void* d_ws, size_t ws_size,
                              hipStream_t stream)
{
    const float* hs    = (const float*)d_in[0];
    const float* q_w   = (const float*)d_in[1];
    const float* q_b   = (const float*)d_in[2];
    const float* k_w   = (const float*)d_in[3];
    const float* v_w   = (const float*)d_in[4];
    const float* v_b   = (const float*)d_in[5];
    const float* table = (const float*)d_in[6];
    const int*   rpi   = (const int*)d_in[7];
    float* out = (float*)d_out;

    char* ws = (char*)d_ws;
    size_t off = 0;
    auto alloc = [&](size_t bytes) {
        char* p = ws + off;
        off = (off + bytes + 255) & ~(size_t)255;
        return p;
    };
    bf16_t* hb  = (bf16_t*)alloc((size_t)M_ * D_ * 2);
    bf16_t* Wc  = (bf16_t*)alloc((size_t)NW_ * D_ * 2);
    bf16_t* Qb  = (bf16_t*)alloc((size_t)B_ * H_ * N_ * HD_ * 2);
    bf16_t* Kb  = (bf16_t*)alloc((size_t)B_ * H_ * N_ * HD_ * 2 + 16384); // +pad rows
    bf16_t* VTb = (bf16_t*)alloc((size_t)B_ * H_ * HD_ * VN_ * 2);
    float*  bia = (float*)alloc((size_t)H_ * BPAD_ * BPAD_ * 4);

    int n4h = M_ * D_ / 4;
    cvt_f32_bf16<<<(n4h + 255) / 256, 256, 0, stream>>>(hs, hb, n4h);
    int n4w = D_ * D_ / 4;
    cvt3_f32_bf16<<<dim3((n4w + 255) / 256, 3), 256, 0, stream>>>(
        q_w, k_w, v_w, Wc, n4w);
    build_bias_t<<<BPAD_, 256, 0, stream>>>(table, rpi, bia);

    qkv_gemm<<<2610, 256, 0, stream>>>(hb, Wc, q_b, v_b, Qb, Kb, VTb);

    attn<<<3840, 256, 0, stream>>>(Qb, Kb, VTb, bia, out);
}